// Round 10
// baseline (308.992 us; speedup 1.0000x reference)
//
#include <hip/hip_runtime.h>

typedef unsigned short u16;
typedef __attribute__((ext_vector_type(8))) short bf16x8;
typedef __attribute__((ext_vector_type(4))) float f32x4;
typedef __attribute__((ext_vector_type(2))) float f32x2;

constexpr int N_ = 32768;
constexpr int H_ = 128;
constexpr int G_ = 1024;
constexpr int T_ = 2;

__device__ __forceinline__ float sigf(float x){
  float e = __builtin_amdgcn_exp2f(x * -1.44269504f);
  return __builtin_amdgcn_rcpf(1.0f + e);
}
// paired-rcp: 1/dx,1/dy = rcp(dx*dy)*{dy,dx} (1 quarter-rate rcp instead of 2).
__device__ __forceinline__ f32x2 sig2(f32x2 x){
  f32x2 t = x * -1.44269504f;
  f32x2 e; e.x = __builtin_amdgcn_exp2f(t.x); e.y = __builtin_amdgcn_exp2f(t.y);
  f32x2 d = e + 1.0f;
  float r = __builtin_amdgcn_rcpf(d.x * d.y);
  return (f32x2){r * d.y, r * d.x};
}
__device__ __forceinline__ f32x2 tanh2(f32x2 x){
  f32x2 t = x * 2.88539008f;
  f32x2 e; e.x = __builtin_amdgcn_exp2f(t.x); e.y = __builtin_amdgcn_exp2f(t.y);
  f32x2 d = e + 1.0f;
  float r = __builtin_amdgcn_rcpf(d.x * d.y);
  f32x2 rr = (f32x2){r * d.y, r * d.x};
  return 1.0f - 2.0f*rr;
}
__device__ __forceinline__ u16 f2bf(float f){
  unsigned u = __float_as_uint(f);
  unsigned r = (u + 0x7FFFu + ((u>>16)&1u))>>16;
  return (u16)r;
}
__device__ __forceinline__ unsigned cvt_pk_bf16(float a, float b){
  unsigned r;
  asm("v_cvt_pk_bf16_f32 %0, %1, %2" : "=v"(r) : "v"(a), "v"(b));
  return r;
}
__device__ __forceinline__ float bf2f(u16 h){ return __uint_as_float(((unsigned)h)<<16); }
__device__ __forceinline__ float asf(unsigned u){ return __uint_as_float(u); }
__device__ __forceinline__ f32x4 mfma16(bf16x8 a, bf16x8 b, f32x4 c){
  return __builtin_amdgcn_mfma_f32_16x16x32_bf16(a,b,c,0,0,0);
}

// ---------------- unified weight+bias pack (single launch, 417 blocks x 64) ----
__global__ __launch_bounds__(64)
void pack_all(const float* __restrict__ l1Wih, const float* __restrict__ fcs1W,
              const float* __restrict__ l1Whh, const float* __restrict__ fcn1W,
              const float* __restrict__ l2Wih, const float* __restrict__ fcs2W,
              const float* __restrict__ l2Whh, const float* __restrict__ fcn2W,
              const float* __restrict__ l1b, const float* __restrict__ bs1,
              const float* __restrict__ bn1,
              const float* __restrict__ l2b, const float* __restrict__ bs2,
              const float* __restrict__ bn2,
              u16* BY1, u16* BW1, u16* BN1, u16* BY2, u16* BW2, u16* BN2,
              u16* bY1, u16* bY2)
{
  int b = blockIdx.x;
  const int lane = threadIdx.x;
  if (b == 416) {
    for (int i = lane; i < 1024; i += 64) {
      if (i < 384) {
        int p = i; float v;
        if (p < 256) { int o = (p&3)*64 + ((p>>6)<<4) + ((p>>2)&15); v = l1b[o]; }
        else         { int j = p-256; v = bs1[j] + bn1[j]; }
        bY1[p] = f2bf(v);
      } else {
        int p = i - 384; float v;
        if (p < 512) { int o = (p&3)*128 + ((p>>6)<<4) + ((p>>2)&15); v = l2b[o]; }
        else         { int j = p-512; v = bs2[j] + bn2[j]; }
        bY2[p] = f2bf(v);
      }
    }
    return;
  }
  const float* src; u16* dst; int srcNC, NTtot, ntOff, ntCnt, Fh, perm;
  if      (b < 32)  { src=l1Wih; dst=BY1; srcNC=256; NTtot=24; ntOff=0;  ntCnt=16; Fh=64;  perm=2; }
  else if (b < 48)  { src=fcs1W; dst=BY1; srcNC=128; NTtot=24; ntOff=16; ntCnt=8;  Fh=0;   perm=0; b-=32; }
  else if (b < 80)  { src=l1Whh; dst=BW1; srcNC=256; NTtot=16; ntOff=0;  ntCnt=16; Fh=64;  perm=1; b-=48; }
  else if (b < 96)  { src=fcn1W; dst=BN1; srcNC=128; NTtot=8;  ntOff=0;  ntCnt=8;  Fh=0;   perm=0; b-=80; }
  else if (b < 224) { src=l2Wih; dst=BY2; srcNC=512; NTtot=40; ntOff=0;  ntCnt=32; Fh=128; perm=2; b-=96; }
  else if (b < 256) { src=fcs2W; dst=BY2; srcNC=128; NTtot=40; ntOff=32; ntCnt=8;  Fh=0;   perm=0; b-=224; }
  else if (b < 384) { src=l2Whh; dst=BW2; srcNC=512; NTtot=32; ntOff=0;  ntCnt=32; Fh=128; perm=1; b-=256; }
  else              { src=fcn2W; dst=BN2; srcNC=128; NTtot=8;  ntOff=0;  ntCnt=8;  Fh=0;   perm=0; b-=384; }
  const int ntl = b % ntCnt, kt = b / ntCnt;
  const int n = lane & 15, qq = lane >> 4;
  int pr = ntl*16 + n;
  int o;
  if (perm == 1)      o = ((pr>>4)&3)*Fh + ((pr>>6)<<4) + (pr&15);
  else if (perm == 2) o = (pr&3)*Fh + ((pr>>6)<<4) + ((pr>>2)&15);
  else                o = pr;
  u16* d = dst + ((size_t)((kt*NTtot + ntOff + ntl)*64 + lane))*8;
#pragma unroll
  for (int j = 0; j < 8; ++j) {
    int k = kt*32 + qq*8 + j;
    d[j] = f2bf(src[(size_t)k*srcNC + o]);
  }
}

// ---------------- MFMA GEMM: out_bf16[32rows x NTT*16] = A@B + bias -----------
template<int KT, int NTT, int AF32>
__global__ __launch_bounds__(256, 2)
void gemm_kernel(const void* __restrict__ Ain,
                 const u16* __restrict__ Bpk,
                 const u16* __restrict__ biasbf,
                 u16* __restrict__ out, int out_stride)
{
  constexpr int KA  = KT*32;
  constexpr int NTW = NTT/4;
  constexpr int STR = KA + 8;
  __shared__ __align__(16) u16 a_lds[32*STR];
  const int tid  = threadIdx.x;
  const int base = blockIdx.x*32;
  {
    const int sub = tid & 7, rowl = tid >> 3;
    if constexpr (AF32) {
      const float* src = (const float*)Ain + (size_t)(base+rowl)*KA;
#pragma unroll
      for (int cc = 0; cc < KA/32; ++cc) {
        int e0 = (cc*8+sub)*4;
        float4 v = *(const float4*)(src + e0);
        ushort4 bv;
        bv.x = f2bf(v.x); bv.y = f2bf(v.y); bv.z = f2bf(v.z); bv.w = f2bf(v.w);
        *(ushort4*)(void*)(a_lds + rowl*STR + e0) = bv;
      }
    } else {
      const u16* src = (const u16*)Ain + (size_t)(base+rowl)*KA;
#pragma unroll
      for (int cc = 0; cc < KA/64; ++cc) {
        int e0 = (cc*8+sub)*8;
        uint4 v = *(const uint4*)(const void*)(src + e0);
        *(uint4*)(void*)(a_lds + rowl*STR + e0) = v;
      }
    }
  }
  __syncthreads();
  const int lane = tid & 63, w = tid >> 6;
  const int lc = lane & 15, q = lane >> 4;
  f32x4 acc[2][NTW];
  f32x4 z = {0.f,0.f,0.f,0.f};
#pragma unroll
  for (int m = 0; m < 2; ++m)
#pragma unroll
    for (int j = 0; j < NTW; ++j) acc[m][j] = z;
#pragma unroll
  for (int kt = 0; kt < KT; ++kt) {
    bf16x8 af0 = *(const bf16x8*)(const void*)(a_lds + lc*STR      + kt*32 + q*8);
    bf16x8 af1 = *(const bf16x8*)(const void*)(a_lds + (lc+16)*STR + kt*32 + q*8);
#pragma unroll
    for (int j = 0; j < NTW; ++j) {
      bf16x8 bf = *(const bf16x8*)(const void*)(Bpk + ((size_t)((kt*NTT + w*NTW + j)*64 + lane))*8);
      acc[0][j] = mfma16(af0, bf, acc[0][j]);
      acc[1][j] = mfma16(af1, bf, acc[1][j]);
    }
  }
#pragma unroll
  for (int m = 0; m < 2; ++m)
#pragma unroll
    for (int j = 0; j < NTW; ++j) {
      int col = (w*NTW + j)*16 + lc;
#pragma unroll
      for (int r = 0; r < 4; ++r) {
        int row = base + m*16 + q*4 + r;
        out[(size_t)row*out_stride + col] = f2bf(acc[m][j][r] + bf2f(biasbf[col]));
      }
    }
}

// ---------------- LSTM recurrence + fused fc_neigh epilogue -------------------
// gates[M x 4F] = MFMA(h_{t-1}, Whh, C-init = Y[nbr[:,t]] extraction).
// C-init deletes acc zero-init + y pk-adds; gather loads are drained by the
// step barrier's vmcnt(0) before the dependent MFMA issues (no added stall).
template<int KT, int MT, int MW>
__global__ __launch_bounds__(KT*128, MW)
void lstm_kernel(const int* __restrict__ nbr,
                 const u16* __restrict__ Y, int nctot,
                 const u16* __restrict__ Bpk,
                 const u16* __restrict__ BN,
                 const u16* __restrict__ Sp, int s_stride, int s_coloff,
                 u16* __restrict__ out)
{
  constexpr int F   = KT*32;
  constexpr int NW  = KT*2;
  constexpr int NTT = KT*8;
  constexpr int STR = F + 8;
  constexpr int M   = MT*16;
  __shared__ __align__(16) u16 h_lds[2][M*STR];
  __shared__ int nbr_s[M*16];
  const int tid  = threadIdx.x;
  const int base = blockIdx.x * M;
  const int lane = tid & 63, w = tid >> 6;
  const int lc = lane & 15, q = lane >> 4;

  for (int i = tid; i < M*16; i += NW*64) nbr_s[i] = nbr[base*16 + i];

  bf16x8 bfr[KT][4];
#pragma unroll
  for (int kt = 0; kt < KT; ++kt)
#pragma unroll
    for (int g = 0; g < 4; ++g)
      bfr[kt][g] = *(const bf16x8*)(const void*)(Bpk + ((size_t)((kt*NTT + w*4 + g)*64 + lane))*8);

  f32x2 cs[MT][2];
#pragma unroll
  for (int m = 0; m < MT; ++m)
#pragma unroll
    for (int rp = 0; rp < 2; ++rp) cs[m][rp] = (f32x2){0.f, 0.f};
  __syncthreads();

  const char* Yb = (const char*)Y;
  const unsigned rowbytes = (unsigned)nctot * 2u;
  const unsigned lanebyte = (unsigned)(w*64 + lc*4) * 2u;
  const int wcol = w*16 + lc;

  uint2 yv[MT][4];
#pragma unroll
  for (int m = 0; m < MT; ++m)
#pragma unroll
    for (int r = 0; r < 4; ++r) {
      unsigned vr = (unsigned)nbr_s[(m*16 + q*4 + r)*16];
      yv[m][r] = *(const uint2*)(const void*)(Yb + (vr*rowbytes + lanebyte));
    }

  for (int t = 0; t < 16; ++t) {
    const u16* hr = h_lds[t & 1];
    u16*       hw = h_lds[(t & 1) ^ 1];
#pragma unroll
    for (int m = 0; m < MT; ++m) {
      // C-init from gathered Y (gate-interleaved: .x = i|f, .y = g|o)
      f32x4 acc[4];
#pragma unroll
      for (int r = 0; r < 4; ++r) {
        acc[0][r] = asf(yv[m][r].x << 16);
        acc[1][r] = asf(yv[m][r].x & 0xffff0000u);
        acc[2][r] = asf(yv[m][r].y << 16);
        acc[3][r] = asf(yv[m][r].y & 0xffff0000u);
      }
      if (t != 0) {
#pragma unroll
        for (int kt = 0; kt < KT; ++kt) {
          bf16x8 af = *(const bf16x8*)(const void*)(hr + (lc + m*16)*STR + kt*32 + q*8);
#pragma unroll
          for (int g = 0; g < 4; ++g) acc[g] = mfma16(af, bfr[kt][g], acc[g]);
        }
      }
#pragma unroll
      for (int rp = 0; rp < 2; ++rp) {
        f32x2 gi = (f32x2){acc[0][2*rp], acc[0][2*rp+1]};
        f32x2 gf = (f32x2){acc[1][2*rp], acc[1][2*rp+1]};
        f32x2 gg = (f32x2){acc[2][2*rp], acc[2][2*rp+1]};
        f32x2 go = (f32x2){acc[3][2*rp], acc[3][2*rp+1]};
        f32x2 c  = sig2(gf)*cs[m][rp] + sig2(gi)*tanh2(gg);
        cs[m][rp] = c;
        f32x2 hh = sig2(go)*tanh2(c);
        unsigned pkd = cvt_pk_bf16(hh.x, hh.y);
        int r0 = m*16 + q*4 + 2*rp;
        hw[r0*STR + wcol]     = (u16)pkd;
        hw[(r0+1)*STR + wcol] = (u16)(pkd >> 16);
      }
    }
    if (t < 15) {                      // prefetch y(t+1); drained at the barrier
#pragma unroll
      for (int m = 0; m < MT; ++m)
#pragma unroll
        for (int r = 0; r < 4; ++r) {
          unsigned vr = (unsigned)nbr_s[(m*16 + q*4 + r)*16 + t + 1];
          yv[m][r] = *(const uint2*)(const void*)(Yb + (vr*rowbytes + lanebyte));
        }
    }
    __syncthreads();
  }

  // ---- fused fc_neigh + sigmoid epilogue (h_K in h_lds[0]) ----
  constexpr int CPW = 8 / NW;
  const u16* hf = h_lds[0];
#pragma unroll
  for (int cc2 = 0; cc2 < CPW; ++cc2) {
    const int nt = w*CPW + cc2;
    f32x4 a2[MT];
    f32x4 z = {0.f,0.f,0.f,0.f};
#pragma unroll
    for (int m = 0; m < MT; ++m) a2[m] = z;
#pragma unroll
    for (int kt = 0; kt < KT; ++kt) {
      bf16x8 nf = *(const bf16x8*)(const void*)(BN + ((size_t)((kt*8 + nt)*64 + lane))*8);
#pragma unroll
      for (int m = 0; m < MT; ++m) {
        bf16x8 af = *(const bf16x8*)(const void*)(hf + (lc + m*16)*STR + kt*32 + q*8);
        a2[m] = mfma16(af, nf, a2[m]);
      }
    }
    const int col = nt*16 + lc;
#pragma unroll
    for (int m = 0; m < MT; ++m)
#pragma unroll
      for (int r = 0; r < 4; ++r) {
        int row = base + m*16 + q*4 + r;
        float v = a2[m][r] + bf2f(Sp[(size_t)row*s_stride + s_coloff + col]);
        out[(size_t)row*H_ + col] = f2bf(sigf(v));
      }
  }
}

// ---------------- readout + head (graphs = 32 contiguous nodes) --------------
__global__ __launch_bounds__(128)
void head_kernel(const u16* __restrict__ h2, const float* __restrict__ rwW,
                 const float* __restrict__ rwb,
                 const float* __restrict__ h1W, const float* __restrict__ h1b,
                 const float* __restrict__ h2W, const float* __restrict__ h2b,
                 float* __restrict__ out)
{
  __shared__ float h2s[32*H_];
  __shared__ float part[32*4];
  __shared__ float wv[32];
  __shared__ float gemb[2*H_];
  __shared__ float y1[H_];
  const int g = blockIdx.x, t = threadIdx.x;
  for (int r = 0; r < 32; ++r)
    h2s[r*H_ + t] = bf2f(h2[(size_t)(g*32 + r)*H_ + t]);
  __syncthreads();
  { int r = t>>2, qq = t&3; float p = 0.f;
    for (int h = qq*32; h < qq*32+32; ++h) p += h2s[r*H_+h]*rwW[h];
    part[r*4+qq] = p; }
  __syncthreads();
  if (t < 32) wv[t] = sigf(part[t*4]+part[t*4+1]+part[t*4+2]+part[t*4+3]+rwb[0]);
  __syncthreads();
  { float wsum=0.f, mx=-3.402823466e38f;
    for (int r = 0; r < 32; ++r) { float v = h2s[r*H_+t]; wsum += wv[r]*v; mx = fmaxf(mx,v); }
    gemb[t]=wsum; gemb[H_+t]=mx; }
  __syncthreads();
  { float a = h1b[t];
    for (int k = 0; k < 2*H_; ++k) a += gemb[k]*h1W[k*H_+t];
    y1[t]=sigf(a); }
  __syncthreads();
  if (t < T_) {
    float a = h2b[t];
    for (int h = 0; h < H_; ++h) a += y1[h]*h2W[h*T_+t];
    out[(size_t)g*T_+t] = sigf(a);
  }
}

extern "C" void kernel_launch(void* const* d_in, const int* in_sizes, int n_in,
                              void* d_out, int out_size, void* d_ws, size_t ws_size,
                              hipStream_t stream) {
  const float* n_feat = (const float*)d_in[0];
  const int*   nbr    = (const int*)d_in[1];
  const float* l1Wih = (const float*)d_in[4];
  const float* l1Whh = (const float*)d_in[5];
  const float* l1b   = (const float*)d_in[6];
  const float* fcs1W = (const float*)d_in[7];
  const float* fcs1b = (const float*)d_in[8];
  const float* fcn1W = (const float*)d_in[9];
  const float* fcn1b = (const float*)d_in[10];
  const float* l2Wih = (const float*)d_in[11];
  const float* l2Whh = (const float*)d_in[12];
  const float* l2b   = (const float*)d_in[13];
  const float* fcs2W = (const float*)d_in[14];
  const float* fcs2b = (const float*)d_in[15];
  const float* fcn2W = (const float*)d_in[16];
  const float* fcn2b = (const float*)d_in[17];
  const float* rwW   = (const float*)d_in[18];
  const float* rwb   = (const float*)d_in[19];
  const float* h1W   = (const float*)d_in[20];
  const float* h1b   = (const float*)d_in[21];
  const float* h2W   = (const float*)d_in[22];
  const float* h2b   = (const float*)d_in[23];

  char* ws = (char*)d_ws;
  u16* Y   = (u16*)(ws);                         // [N x 640] max = 40 MB
  u16* h1  = (u16*)(ws + 41943040);              // [N x 128] bf16
  u16* h2  = (u16*)(ws + 50331648);              // [N x 128] bf16
  char* wt = ws + 58720256;
  u16* BY1 = (u16*)(wt);
  u16* BW1 = (u16*)(wt + 49152);
  u16* BN1 = (u16*)(wt + 81920);
  u16* BY2 = (u16*)(wt + 98304);
  u16* BW2 = (u16*)(wt + 262144);
  u16* BN2 = (u16*)(wt + 393216);
  u16* bY1 = (u16*)(wt + 425984);
  u16* bY2 = (u16*)(wt + 426752);

  pack_all<<<417, 64, 0, stream>>>(l1Wih, fcs1W, l1Whh, fcn1W,
                                   l2Wih, fcs2W, l2Whh, fcn2W,
                                   l1b, fcs1b, fcn1b, l2b, fcs2b, fcn2b,
                                   BY1, BW1, BN1, BY2, BW2, BN2, bY1, bY2);

  gemm_kernel<2,24,1><<<1024, 256, 0, stream>>>(n_feat, BY1, bY1, Y, 384);
  lstm_kernel<2,1,6><<<2048, 256, 0, stream>>>(nbr, Y, 384, BW1, BN1, Y, 384, 256, h1);

  gemm_kernel<4,40,0><<<1024, 256, 0, stream>>>(h1, BY2, bY2, Y, 640);
  lstm_kernel<4,1,4><<<2048, 512, 0, stream>>>(nbr, Y, 640, BW2, BN2, Y, 640, 512, h2);

  head_kernel<<<G_, 128, 0, stream>>>(h2, rwW, rwb, h1W, h1b, h2W, h2b, (float*)d_out);
}

// Round 11
// 280.471 us; speedup vs baseline: 1.1017x; 1.1017x over previous
//
#include <hip/hip_runtime.h>

typedef unsigned short u16;
typedef __attribute__((ext_vector_type(8))) short bf16x8;
typedef __attribute__((ext_vector_type(4))) float f32x4;
typedef __attribute__((ext_vector_type(2))) float f32x2;

constexpr int N_ = 32768;
constexpr int H_ = 128;
constexpr int G_ = 1024;
constexpr int T_ = 2;

// Gate pre-scale folded into weights/bias at pack time:
//   i,f,o cols scaled by -log2(e); g cols by +2*log2(e).
// So sig2p/tanh2p take pre-scaled inputs (no v_pk_mul).
__device__ __forceinline__ float sigf(float x){
  float e = __builtin_amdgcn_exp2f(x * -1.44269504f);
  return __builtin_amdgcn_rcpf(1.0f + e);
}
__device__ __forceinline__ f32x2 sig2p(f32x2 xp){   // xp = -log2e * x
  f32x2 e; e.x = __builtin_amdgcn_exp2f(xp.x); e.y = __builtin_amdgcn_exp2f(xp.y);
  f32x2 d = e + 1.0f;
  float r = __builtin_amdgcn_rcpf(d.x * d.y);
  return (f32x2){r * d.y, r * d.x};
}
__device__ __forceinline__ f32x2 tanh2p(f32x2 xp){  // xp = 2*log2e * x
  f32x2 e; e.x = __builtin_amdgcn_exp2f(xp.x); e.y = __builtin_amdgcn_exp2f(xp.y);
  f32x2 d = e + 1.0f;
  float r = __builtin_amdgcn_rcpf(d.x * d.y);
  f32x2 rr = (f32x2){r * d.y, r * d.x};
  return 1.0f - 2.0f*rr;
}
__device__ __forceinline__ f32x2 tanh2(f32x2 x){    // unscaled input (cell state)
  f32x2 t = x * 2.88539008f;
  f32x2 e; e.x = __builtin_amdgcn_exp2f(t.x); e.y = __builtin_amdgcn_exp2f(t.y);
  f32x2 d = e + 1.0f;
  float r = __builtin_amdgcn_rcpf(d.x * d.y);
  f32x2 rr = (f32x2){r * d.y, r * d.x};
  return 1.0f - 2.0f*rr;
}
__device__ __forceinline__ u16 f2bf(float f){
  unsigned u = __float_as_uint(f);
  unsigned r = (u + 0x7FFFu + ((u>>16)&1u))>>16;
  return (u16)r;
}
__device__ __forceinline__ unsigned cvt_pk_bf16(float a, float b){
  unsigned r;
  asm("v_cvt_pk_bf16_f32 %0, %1, %2" : "=v"(r) : "v"(a), "v"(b));
  return r;
}
__device__ __forceinline__ float bf2f(u16 h){ return __uint_as_float(((unsigned)h)<<16); }
__device__ __forceinline__ float asf(unsigned u){ return __uint_as_float(u); }
__device__ __forceinline__ f32x4 mfma16(bf16x8 a, bf16x8 b, f32x4 c){
  return __builtin_amdgcn_mfma_f32_16x16x32_bf16(a,b,c,0,0,0);
}

// ---------------- unified weight+bias pack (single launch, 417 blocks x 64) ----
__global__ __launch_bounds__(64)
void pack_all(const float* __restrict__ l1Wih, const float* __restrict__ fcs1W,
              const float* __restrict__ l1Whh, const float* __restrict__ fcn1W,
              const float* __restrict__ l2Wih, const float* __restrict__ fcs2W,
              const float* __restrict__ l2Whh, const float* __restrict__ fcn2W,
              const float* __restrict__ l1b, const float* __restrict__ bs1,
              const float* __restrict__ bn1,
              const float* __restrict__ l2b, const float* __restrict__ bs2,
              const float* __restrict__ bn2,
              u16* BY1, u16* BW1, u16* BN1, u16* BY2, u16* BW2, u16* BN2,
              u16* bY1, u16* bY2)
{
  int b = blockIdx.x;
  const int lane = threadIdx.x;
  if (b == 416) {
    for (int i = lane; i < 1024; i += 64) {
      if (i < 384) {
        int p = i; float v;
        if (p < 256) {
          int o = (p&3)*64 + ((p>>6)<<4) + ((p>>2)&15);
          float sc = ((p&3)==2) ? 2.88539008f : -1.44269504f;
          v = l1b[o]*sc;
        } else { int j = p-256; v = bs1[j] + bn1[j]; }
        bY1[p] = f2bf(v);
      } else {
        int p = i - 384; float v;
        if (p < 512) {
          int o = (p&3)*128 + ((p>>6)<<4) + ((p>>2)&15);
          float sc = ((p&3)==2) ? 2.88539008f : -1.44269504f;
          v = l2b[o]*sc;
        } else { int j = p-512; v = bs2[j] + bn2[j]; }
        bY2[p] = f2bf(v);
      }
    }
    return;
  }
  const float* src; u16* dst; int srcNC, NTtot, ntOff, ntCnt, Fh, perm;
  if      (b < 32)  { src=l1Wih; dst=BY1; srcNC=256; NTtot=24; ntOff=0;  ntCnt=16; Fh=64;  perm=2; }
  else if (b < 48)  { src=fcs1W; dst=BY1; srcNC=128; NTtot=24; ntOff=16; ntCnt=8;  Fh=0;   perm=0; b-=32; }
  else if (b < 80)  { src=l1Whh; dst=BW1; srcNC=256; NTtot=16; ntOff=0;  ntCnt=16; Fh=64;  perm=1; b-=48; }
  else if (b < 96)  { src=fcn1W; dst=BN1; srcNC=128; NTtot=8;  ntOff=0;  ntCnt=8;  Fh=0;   perm=0; b-=80; }
  else if (b < 224) { src=l2Wih; dst=BY2; srcNC=512; NTtot=40; ntOff=0;  ntCnt=32; Fh=128; perm=2; b-=96; }
  else if (b < 256) { src=fcs2W; dst=BY2; srcNC=128; NTtot=40; ntOff=32; ntCnt=8;  Fh=0;   perm=0; b-=224; }
  else if (b < 384) { src=l2Whh; dst=BW2; srcNC=512; NTtot=32; ntOff=0;  ntCnt=32; Fh=128; perm=1; b-=256; }
  else              { src=fcn2W; dst=BN2; srcNC=128; NTtot=8;  ntOff=0;  ntCnt=8;  Fh=0;   perm=0; b-=384; }
  const int ntl = b % ntCnt, kt = b / ntCnt;
  const int n = lane & 15, qq = lane >> 4;
  int pr = ntl*16 + n;
  int o; float scale = 1.0f;
  if (perm == 1) {
    int g = (pr>>4)&3;
    o = g*Fh + ((pr>>6)<<4) + (pr&15);
    scale = (g==2) ? 2.88539008f : -1.44269504f;
  } else if (perm == 2) {
    int g = pr&3;
    o = g*Fh + ((pr>>6)<<4) + ((pr>>2)&15);
    scale = (g==2) ? 2.88539008f : -1.44269504f;
  } else o = pr;
  u16* d = dst + ((size_t)((kt*NTtot + ntOff + ntl)*64 + lane))*8;
#pragma unroll
  for (int j = 0; j < 8; ++j) {
    int k = kt*32 + qq*8 + j;
    d[j] = f2bf(src[(size_t)k*srcNC + o] * scale);
  }
}

// ---------------- MFMA GEMM: out_bf16[32rows x NTT*16] = A@B + bias -----------
template<int KT, int NTT, int AF32>
__global__ __launch_bounds__(256, 2)
void gemm_kernel(const void* __restrict__ Ain,
                 const u16* __restrict__ Bpk,
                 const u16* __restrict__ biasbf,
                 u16* __restrict__ out, int out_stride)
{
  constexpr int KA  = KT*32;
  constexpr int NTW = NTT/4;
  constexpr int STR = KA + 8;
  __shared__ __align__(16) u16 a_lds[32*STR];
  const int tid  = threadIdx.x;
  const int base = blockIdx.x*32;
  {
    const int sub = tid & 7, rowl = tid >> 3;
    if constexpr (AF32) {
      const float* src = (const float*)Ain + (size_t)(base+rowl)*KA;
#pragma unroll
      for (int cc = 0; cc < KA/32; ++cc) {
        int e0 = (cc*8+sub)*4;
        float4 v = *(const float4*)(src + e0);
        ushort4 bv;
        bv.x = f2bf(v.x); bv.y = f2bf(v.y); bv.z = f2bf(v.z); bv.w = f2bf(v.w);
        *(ushort4*)(void*)(a_lds + rowl*STR + e0) = bv;
      }
    } else {
      const u16* src = (const u16*)Ain + (size_t)(base+rowl)*KA;
#pragma unroll
      for (int cc = 0; cc < KA/64; ++cc) {
        int e0 = (cc*8+sub)*8;
        uint4 v = *(const uint4*)(const void*)(src + e0);
        *(uint4*)(void*)(a_lds + rowl*STR + e0) = v;
      }
    }
  }
  __syncthreads();
  const int lane = tid & 63, w = tid >> 6;
  const int lc = lane & 15, q = lane >> 4;
  f32x4 acc[2][NTW];
  f32x4 z = {0.f,0.f,0.f,0.f};
#pragma unroll
  for (int m = 0; m < 2; ++m)
#pragma unroll
    for (int j = 0; j < NTW; ++j) acc[m][j] = z;
#pragma unroll
  for (int kt = 0; kt < KT; ++kt) {
    bf16x8 af0 = *(const bf16x8*)(const void*)(a_lds + lc*STR      + kt*32 + q*8);
    bf16x8 af1 = *(const bf16x8*)(const void*)(a_lds + (lc+16)*STR + kt*32 + q*8);
#pragma unroll
    for (int j = 0; j < NTW; ++j) {
      bf16x8 bf = *(const bf16x8*)(const void*)(Bpk + ((size_t)((kt*NTT + w*NTW + j)*64 + lane))*8);
      acc[0][j] = mfma16(af0, bf, acc[0][j]);
      acc[1][j] = mfma16(af1, bf, acc[1][j]);
    }
  }
#pragma unroll
  for (int m = 0; m < 2; ++m)
#pragma unroll
    for (int j = 0; j < NTW; ++j) {
      int col = (w*NTW + j)*16 + lc;
#pragma unroll
      for (int r = 0; r < 4; ++r) {
        int row = base + m*16 + q*4 + r;
        out[(size_t)row*out_stride + col] = f2bf(acc[m][j][r] + bf2f(biasbf[col]));
      }
    }
}

// ---------------- LSTM recurrence + fused fc_neigh epilogue -------------------
// gates[M x 4F] = MFMA(h_{t-1}, Whh, C-init = Y[nbr[:,t]] extraction), prescaled.
template<int KT, int MT, int MW>
__global__ __launch_bounds__(KT*128, MW)
void lstm_kernel(const int* __restrict__ nbr,
                 const u16* __restrict__ Y, int nctot,
                 const u16* __restrict__ Bpk,
                 const u16* __restrict__ BN,
                 const u16* __restrict__ Sp, int s_stride, int s_coloff,
                 u16* __restrict__ out)
{
  constexpr int F   = KT*32;
  constexpr int NW  = KT*2;
  constexpr int NTT = KT*8;
  constexpr int STR = F + 8;
  constexpr int M   = MT*16;
  __shared__ __align__(16) u16 h_lds[2][M*STR];
  __shared__ int nbr_s[M*16];
  const int tid  = threadIdx.x;
  const int base = blockIdx.x * M;
  const int lane = tid & 63, w = tid >> 6;
  const int lc = lane & 15, q = lane >> 4;

  for (int i = tid; i < M*16; i += NW*64) nbr_s[i] = nbr[base*16 + i];

  bf16x8 bfr[KT][4];
#pragma unroll
  for (int kt = 0; kt < KT; ++kt)
#pragma unroll
    for (int g = 0; g < 4; ++g)
      bfr[kt][g] = *(const bf16x8*)(const void*)(Bpk + ((size_t)((kt*NTT + w*4 + g)*64 + lane))*8);

  f32x2 cs[MT][2];
#pragma unroll
  for (int m = 0; m < MT; ++m)
#pragma unroll
    for (int rp = 0; rp < 2; ++rp) cs[m][rp] = (f32x2){0.f, 0.f};
  __syncthreads();

  const char* Yb = (const char*)Y;
  const unsigned rowbytes = (unsigned)nctot * 2u;
  const unsigned lanebyte = (unsigned)(w*64 + lc*4) * 2u;
  const int wcol = w*16 + lc;

  uint2 yv[MT][4];
#pragma unroll
  for (int m = 0; m < MT; ++m)
#pragma unroll
    for (int r = 0; r < 4; ++r) {
      unsigned vr = (unsigned)nbr_s[(m*16 + q*4 + r)*16];
      yv[m][r] = *(const uint2*)(const void*)(Yb + (vr*rowbytes + lanebyte));
    }

  for (int t = 0; t < 16; ++t) {
    const u16* hr = h_lds[t & 1];
    u16*       hw = h_lds[(t & 1) ^ 1];
#pragma unroll
    for (int m = 0; m < MT; ++m) {
      f32x4 acc[4];
#pragma unroll
      for (int r = 0; r < 4; ++r) {
        acc[0][r] = asf(yv[m][r].x << 16);
        acc[1][r] = asf(yv[m][r].x & 0xffff0000u);
        acc[2][r] = asf(yv[m][r].y << 16);
        acc[3][r] = asf(yv[m][r].y & 0xffff0000u);
      }
      if (t != 0) {
#pragma unroll
        for (int kt = 0; kt < KT; ++kt) {
          bf16x8 af = *(const bf16x8*)(const void*)(hr + (lc + m*16)*STR + kt*32 + q*8);
#pragma unroll
          for (int g = 0; g < 4; ++g) acc[g] = mfma16(af, bfr[kt][g], acc[g]);
        }
      }
#pragma unroll
      for (int rp = 0; rp < 2; ++rp) {
        f32x2 gi = (f32x2){acc[0][2*rp], acc[0][2*rp+1]};
        f32x2 gf = (f32x2){acc[1][2*rp], acc[1][2*rp+1]};
        f32x2 gg = (f32x2){acc[2][2*rp], acc[2][2*rp+1]};
        f32x2 go = (f32x2){acc[3][2*rp], acc[3][2*rp+1]};
        f32x2 c  = sig2p(gf)*cs[m][rp] + sig2p(gi)*tanh2p(gg);
        cs[m][rp] = c;
        f32x2 hh = sig2p(go)*tanh2(c);
        unsigned pkd = cvt_pk_bf16(hh.x, hh.y);
        int r0 = m*16 + q*4 + 2*rp;
        hw[r0*STR + wcol]     = (u16)pkd;
        hw[(r0+1)*STR + wcol] = (u16)(pkd >> 16);
      }
    }
    if (t < 15) {
#pragma unroll
      for (int m = 0; m < MT; ++m)
#pragma unroll
        for (int r = 0; r < 4; ++r) {
          unsigned vr = (unsigned)nbr_s[(m*16 + q*4 + r)*16 + t + 1];
          yv[m][r] = *(const uint2*)(const void*)(Yb + (vr*rowbytes + lanebyte));
        }
    }
    __syncthreads();
  }

  constexpr int CPW = 8 / NW;
  const u16* hf = h_lds[0];
#pragma unroll
  for (int cc2 = 0; cc2 < CPW; ++cc2) {
    const int nt = w*CPW + cc2;
    f32x4 a2[MT];
    f32x4 z = {0.f,0.f,0.f,0.f};
#pragma unroll
    for (int m = 0; m < MT; ++m) a2[m] = z;
#pragma unroll
    for (int kt = 0; kt < KT; ++kt) {
      bf16x8 nf = *(const bf16x8*)(const void*)(BN + ((size_t)((kt*8 + nt)*64 + lane))*8);
#pragma unroll
      for (int m = 0; m < MT; ++m) {
        bf16x8 af = *(const bf16x8*)(const void*)(hf + (lc + m*16)*STR + kt*32 + q*8);
        a2[m] = mfma16(af, nf, a2[m]);
      }
    }
    const int col = nt*16 + lc;
#pragma unroll
    for (int m = 0; m < MT; ++m)
#pragma unroll
      for (int r = 0; r < 4; ++r) {
        int row = base + m*16 + q*4 + r;
        float v = a2[m][r] + bf2f(Sp[(size_t)row*s_stride + s_coloff + col]);
        out[(size_t)row*H_ + col] = f2bf(sigf(v));
      }
  }
}

// ---------------- layer-1 LSTM with fused fc epilogue AND Y2 GEMM ------------
// After h1 = sigmoid(S + h_K@Wn) is computed, stage h1 in LDS and compute
// Y2[16 x 640] = h1 @ BY2 + bY2 directly (kills gemm2 + 16 MB h1 round-trip).
__global__ __launch_bounds__(256, 6)
void lstm1_y2(const int* __restrict__ nbr,
              const u16* __restrict__ Y1,        // [N x 384] gates(256,prescaled)+S(128)
              const u16* __restrict__ Bpk,       // Whh1
              const u16* __restrict__ BN,        // fcn1W
              const u16* __restrict__ BY2,       // [Wih2 perm2 | fcs2W], K=128, NTT=40
              const u16* __restrict__ bY2,       // 640
              u16* __restrict__ Y2)              // [N x 640]
{
  constexpr int STR = 72;
  __shared__ __align__(16) u16 h_lds[2][16*STR];
  __shared__ __align__(16) u16 hs[16*136];       // h1 staged for Y2 GEMM
  __shared__ int nbr_s[256];
  const int tid  = threadIdx.x;
  const int base = blockIdx.x * 16;
  const int lane = tid & 63, w = tid >> 6;
  const int lc = lane & 15, q = lane >> 4;

  nbr_s[tid] = nbr[base*16 + tid];

  bf16x8 bfr[2][4];
#pragma unroll
  for (int kt = 0; kt < 2; ++kt)
#pragma unroll
    for (int g = 0; g < 4; ++g)
      bfr[kt][g] = *(const bf16x8*)(const void*)(Bpk + ((size_t)((kt*16 + w*4 + g)*64 + lane))*8);

  f32x2 cs[2];
  cs[0] = (f32x2){0.f,0.f}; cs[1] = (f32x2){0.f,0.f};
  __syncthreads();

  const char* Yb = (const char*)Y1;
  const unsigned lanebyte = (unsigned)(w*64 + lc*4) * 2u;
  const int wcol = w*16 + lc;

  uint2 yv[4];
#pragma unroll
  for (int r = 0; r < 4; ++r) {
    unsigned vr = (unsigned)nbr_s[(q*4 + r)*16];
    yv[r] = *(const uint2*)(const void*)(Yb + (vr*768u + lanebyte));
  }

  for (int t = 0; t < 16; ++t) {
    const u16* hr = h_lds[t & 1];
    u16*       hw = h_lds[(t & 1) ^ 1];
    f32x4 acc[4];
#pragma unroll
    for (int r = 0; r < 4; ++r) {
      acc[0][r] = asf(yv[r].x << 16);
      acc[1][r] = asf(yv[r].x & 0xffff0000u);
      acc[2][r] = asf(yv[r].y << 16);
      acc[3][r] = asf(yv[r].y & 0xffff0000u);
    }
    if (t != 0) {
#pragma unroll
      for (int kt = 0; kt < 2; ++kt) {
        bf16x8 af = *(const bf16x8*)(const void*)(hr + lc*STR + kt*32 + q*8);
#pragma unroll
        for (int g = 0; g < 4; ++g) acc[g] = mfma16(af, bfr[kt][g], acc[g]);
      }
    }
#pragma unroll
    for (int rp = 0; rp < 2; ++rp) {
      f32x2 gi = (f32x2){acc[0][2*rp], acc[0][2*rp+1]};
      f32x2 gf = (f32x2){acc[1][2*rp], acc[1][2*rp+1]};
      f32x2 gg = (f32x2){acc[2][2*rp], acc[2][2*rp+1]};
      f32x2 go = (f32x2){acc[3][2*rp], acc[3][2*rp+1]};
      f32x2 c  = sig2p(gf)*cs[rp] + sig2p(gi)*tanh2p(gg);
      cs[rp] = c;
      f32x2 hh = sig2p(go)*tanh2(c);
      unsigned pkd = cvt_pk_bf16(hh.x, hh.y);
      int r0 = q*4 + 2*rp;
      hw[r0*STR + wcol]     = (u16)pkd;
      hw[(r0+1)*STR + wcol] = (u16)(pkd >> 16);
    }
    if (t < 15) {
#pragma unroll
      for (int r = 0; r < 4; ++r) {
        unsigned vr = (unsigned)nbr_s[(q*4 + r)*16 + t + 1];
        yv[r] = *(const uint2*)(const void*)(Yb + (vr*768u + lanebyte));
      }
    }
    __syncthreads();
  }

  // ---- epilogue 1: h1 = sigmoid(S + h_K@Wn) -> hs (LDS) ----
  const u16* hf = h_lds[0];
#pragma unroll
  for (int cc2 = 0; cc2 < 2; ++cc2) {
    const int nt = w*2 + cc2;
    f32x4 a2 = {0.f,0.f,0.f,0.f};
#pragma unroll
    for (int kt = 0; kt < 2; ++kt) {
      bf16x8 nf = *(const bf16x8*)(const void*)(BN + ((size_t)((kt*8 + nt)*64 + lane))*8);
      bf16x8 af = *(const bf16x8*)(const void*)(hf + lc*STR + kt*32 + q*8);
      a2 = mfma16(af, nf, a2);
    }
    const int col = nt*16 + lc;
#pragma unroll
    for (int r = 0; r < 4; ++r) {
      int row = base + q*4 + r;
      float v = a2[r] + bf2f(Y1[(size_t)row*384 + 256 + col]);
      hs[(q*4 + r)*136 + col] = f2bf(sigf(v));
    }
  }
  __syncthreads();

  // ---- epilogue 2: Y2 = h1 @ BY2 + bY2 (K=128, 640 cols; 10 ntiles/wave) ----
#pragma unroll
  for (int j = 0; j < 10; ++j) {
    const int nt = w*10 + j;
    const int col = nt*16 + lc;
    float bv = bf2f(bY2[col]);
    f32x4 acc;
#pragma unroll
    for (int r = 0; r < 4; ++r) acc[r] = bv;
#pragma unroll
    for (int kt = 0; kt < 4; ++kt) {
      bf16x8 af = *(const bf16x8*)(const void*)(hs + lc*136 + kt*32 + q*8);
      bf16x8 bf = *(const bf16x8*)(const void*)(BY2 + ((size_t)((kt*40 + nt)*64 + lane))*8);
      acc = mfma16(af, bf, acc);
    }
#pragma unroll
    for (int r = 0; r < 4; ++r)
      Y2[(size_t)(base + q*4 + r)*640 + col] = f2bf(acc[r]);
  }
}

// ---------------- readout + head (graphs = 32 contiguous nodes) --------------
__global__ __launch_bounds__(128)
void head_kernel(const u16* __restrict__ h2, const float* __restrict__ rwW,
                 const float* __restrict__ rwb,
                 const float* __restrict__ h1W, const float* __restrict__ h1b,
                 const float* __restrict__ h2W, const float* __restrict__ h2b,
                 float* __restrict__ out)
{
  __shared__ float h2s[32*H_];
  __shared__ float part[32*4];
  __shared__ float wv[32];
  __shared__ float gemb[2*H_];
  __shared__ float y1[H_];
  const int g = blockIdx.x, t = threadIdx.x;
  for (int r = 0; r < 32; ++r)
    h2s[r*H_ + t] = bf2f(h2[(size_t)(g*32 + r)*H_ + t]);
  __syncthreads();
  { int r = t>>2, qq = t&3; float p = 0.f;
    for (int h = qq*32; h < qq*32+32; ++h) p += h2s[r*H_+h]*rwW[h];
    part[r*4+qq] = p; }
  __syncthreads();
  if (t < 32) wv[t] = sigf(part[t*4]+part[t*4+1]+part[t*4+2]+part[t*4+3]+rwb[0]);
  __syncthreads();
  { float wsum=0.f, mx=-3.402823466e38f;
    for (int r = 0; r < 32; ++r) { float v = h2s[r*H_+t]; wsum += wv[r]*v; mx = fmaxf(mx,v); }
    gemb[t]=wsum; gemb[H_+t]=mx; }
  __syncthreads();
  { float a = h1b[t];
    for (int k = 0; k < 2*H_; ++k) a += gemb[k]*h1W[k*H_+t];
    y1[t]=sigf(a); }
  __syncthreads();
  if (t < T_) {
    float a = h2b[t];
    for (int h = 0; h < H_; ++h) a += y1[h]*h2W[h*T_+t];
    out[(size_t)g*T_+t] = sigf(a);
  }
}

extern "C" void kernel_launch(void* const* d_in, const int* in_sizes, int n_in,
                              void* d_out, int out_size, void* d_ws, size_t ws_size,
                              hipStream_t stream) {
  const float* n_feat = (const float*)d_in[0];
  const int*   nbr    = (const int*)d_in[1];
  const float* l1Wih = (const float*)d_in[4];
  const float* l1Whh = (const float*)d_in[5];
  const float* l1b   = (const float*)d_in[6];
  const float* fcs1W = (const float*)d_in[7];
  const float* fcs1b = (const float*)d_in[8];
  const float* fcn1W = (const float*)d_in[9];
  const float* fcn1b = (const float*)d_in[10];
  const float* l2Wih = (const float*)d_in[11];
  const float* l2Whh = (const float*)d_in[12];
  const float* l2b   = (const float*)d_in[13];
  const float* fcs2W = (const float*)d_in[14];
  const float* fcs2b = (const float*)d_in[15];
  const float* fcn2W = (const float*)d_in[16];
  const float* fcn2b = (const float*)d_in[17];
  const float* rwW   = (const float*)d_in[18];
  const float* rwb   = (const float*)d_in[19];
  const float* h1W   = (const float*)d_in[20];
  const float* h1b   = (const float*)d_in[21];
  const float* h2W   = (const float*)d_in[22];
  const float* h2b   = (const float*)d_in[23];

  char* ws = (char*)d_ws;

  if (ws_size >= 67600000) {
    // ---- fused path: separate Y1/Y2, no gemm2, no h1 round-trip ----
    u16* Y1 = (u16*)(ws);                        // [N x 384] = 25.2 MB
    u16* Y2 = (u16*)(ws + 25165824);             // [N x 640] = 41.9 MB (end 67.1 MB)
    u16* h2 = (u16*)(ws);                        // reuse Y1 (dead after lstm1_y2)
    char* wt = ws + 67108864;
    u16* BY1 = (u16*)(wt);
    u16* BW1 = (u16*)(wt + 49152);
    u16* BN1 = (u16*)(wt + 81920);
    u16* BY2 = (u16*)(wt + 98304);
    u16* BW2 = (u16*)(wt + 262144);
    u16* BN2 = (u16*)(wt + 393216);
    u16* bY1 = (u16*)(wt + 425984);
    u16* bY2 = (u16*)(wt + 426752);

    pack_all<<<417, 64, 0, stream>>>(l1Wih, fcs1W, l1Whh, fcn1W,
                                     l2Wih, fcs2W, l2Whh, fcn2W,
                                     l1b, fcs1b, fcn1b, l2b, fcs2b, fcn2b,
                                     BY1, BW1, BN1, BY2, BW2, BN2, bY1, bY2);
    gemm_kernel<2,24,1><<<1024, 256, 0, stream>>>(n_feat, BY1, bY1, Y1, 384);
    lstm1_y2<<<2048, 256, 0, stream>>>(nbr, Y1, BW1, BN1, BY2, bY2, Y2);
    lstm_kernel<4,1,4><<<2048, 512, 0, stream>>>(nbr, Y2, 640, BW2, BN2, Y2, 640, 512, h2);
    head_kernel<<<G_, 128, 0, stream>>>(h2, rwW, rwb, h1W, h1b, h2W, h2b, (float*)d_out);
  } else {
    // ---- fallback: R10 structure (shared Y buffer + gemm2) ----
    u16* Y   = (u16*)(ws);
    u16* h1  = (u16*)(ws + 41943040);
    u16* h2  = (u16*)(ws + 50331648);
    char* wt = ws + 58720256;
    u16* BY1 = (u16*)(wt);
    u16* BW1 = (u16*)(wt + 49152);
    u16* BN1 = (u16*)(wt + 81920);
    u16* BY2 = (u16*)(wt + 98304);
    u16* BW2 = (u16*)(wt + 262144);
    u16* BN2 = (u16*)(wt + 393216);
    u16* bY1 = (u16*)(wt + 425984);
    u16* bY2 = (u16*)(wt + 426752);

    pack_all<<<417, 64, 0, stream>>>(l1Wih, fcs1W, l1Whh, fcn1W,
                                     l2Wih, fcs2W, l2Whh, fcn2W,
                                     l1b, fcs1b, fcn1b, l2b, fcs2b, fcn2b,
                                     BY1, BW1, BN1, BY2, BW2, BN2, bY1, bY2);
    gemm_kernel<2,24,1><<<1024, 256, 0, stream>>>(n_feat, BY1, bY1, Y, 384);
    lstm_kernel<2,1,6><<<2048, 256, 0, stream>>>(nbr, Y, 384, BW1, BN1, Y, 384, 256, h1);
    gemm_kernel<4,40,0><<<1024, 256, 0, stream>>>(h1, BY2, bY2, Y, 640);
    lstm_kernel<4,1,4><<<2048, 512, 0, stream>>>(nbr, Y, 640, BW2, BN2, Y, 640, 512, h2);
    head_kernel<<<G_, 128, 0, stream>>>(h2, rwW, rwb, h1W, h1b, h2W, h2b, (float*)d_out);
  }
}

// Round 12
// 278.159 us; speedup vs baseline: 1.1108x; 1.0083x over previous
//
#include <hip/hip_runtime.h>

typedef unsigned short u16;
typedef __attribute__((ext_vector_type(8))) short bf16x8;
typedef __attribute__((ext_vector_type(4))) float f32x4;
typedef __attribute__((ext_vector_type(2))) float f32x2;

constexpr int N_ = 32768;
constexpr int H_ = 128;
constexpr int G_ = 1024;
constexpr int T_ = 2;

// Gate pre-scale folded into weights/bias at pack time:
//   i,f,o cols scaled by -log2(e); g cols by +2*log2(e).
__device__ __forceinline__ float sigf(float x){
  float e = __builtin_amdgcn_exp2f(x * -1.44269504f);
  return __builtin_amdgcn_rcpf(1.0f + e);
}
__device__ __forceinline__ f32x2 sig2p(f32x2 xp){   // xp = -log2e * x
  f32x2 e; e.x = __builtin_amdgcn_exp2f(xp.x); e.y = __builtin_amdgcn_exp2f(xp.y);
  f32x2 d = e + 1.0f;
  float r = __builtin_amdgcn_rcpf(d.x * d.y);
  return (f32x2){r * d.y, r * d.x};
}
__device__ __forceinline__ f32x2 tanh2p(f32x2 xp){  // xp = 2*log2e * x
  f32x2 e; e.x = __builtin_amdgcn_exp2f(xp.x); e.y = __builtin_amdgcn_exp2f(xp.y);
  f32x2 d = e + 1.0f;
  float r = __builtin_amdgcn_rcpf(d.x * d.y);
  f32x2 rr = (f32x2){r * d.y, r * d.x};
  return 1.0f - 2.0f*rr;
}
__device__ __forceinline__ f32x2 tanh2(f32x2 x){    // unscaled input (cell state)
  f32x2 t = x * 2.88539008f;
  f32x2 e; e.x = __builtin_amdgcn_exp2f(t.x); e.y = __builtin_amdgcn_exp2f(t.y);
  f32x2 d = e + 1.0f;
  float r = __builtin_amdgcn_rcpf(d.x * d.y);
  f32x2 rr = (f32x2){r * d.y, r * d.x};
  return 1.0f - 2.0f*rr;
}
__device__ __forceinline__ u16 f2bf(float f){
  unsigned u = __float_as_uint(f);
  unsigned r = (u + 0x7FFFu + ((u>>16)&1u))>>16;
  return (u16)r;
}
__device__ __forceinline__ unsigned cvt_pk_bf16(float a, float b){
  unsigned r;
  asm("v_cvt_pk_bf16_f32 %0, %1, %2" : "=v"(r) : "v"(a), "v"(b));
  return r;
}
__device__ __forceinline__ float bf2f(u16 h){ return __uint_as_float(((unsigned)h)<<16); }
__device__ __forceinline__ float asf(unsigned u){ return __uint_as_float(u); }
__device__ __forceinline__ f32x4 mfma16(bf16x8 a, bf16x8 b, f32x4 c){
  return __builtin_amdgcn_mfma_f32_16x16x32_bf16(a,b,c,0,0,0);
}

// ---------------- unified weight+bias pack (single launch, 417 blocks x 64) ----
__global__ __launch_bounds__(64)
void pack_all(const float* __restrict__ l1Wih, const float* __restrict__ fcs1W,
              const float* __restrict__ l1Whh, const float* __restrict__ fcn1W,
              const float* __restrict__ l2Wih, const float* __restrict__ fcs2W,
              const float* __restrict__ l2Whh, const float* __restrict__ fcn2W,
              const float* __restrict__ l1b, const float* __restrict__ bs1,
              const float* __restrict__ bn1,
              const float* __restrict__ l2b, const float* __restrict__ bs2,
              const float* __restrict__ bn2,
              u16* BY1, u16* BW1, u16* BN1, u16* BY2, u16* BW2, u16* BN2,
              u16* bY1, u16* bY2)
{
  int b = blockIdx.x;
  const int lane = threadIdx.x;
  if (b == 416) {
    for (int i = lane; i < 1024; i += 64) {
      if (i < 384) {
        int p = i; float v;
        if (p < 256) {
          int o = (p&3)*64 + ((p>>6)<<4) + ((p>>2)&15);
          float sc = ((p&3)==2) ? 2.88539008f : -1.44269504f;
          v = l1b[o]*sc;
        } else { int j = p-256; v = bs1[j] + bn1[j]; }
        bY1[p] = f2bf(v);
      } else {
        int p = i - 384; float v;
        if (p < 512) {
          int o = (p&3)*128 + ((p>>6)<<4) + ((p>>2)&15);
          float sc = ((p&3)==2) ? 2.88539008f : -1.44269504f;
          v = l2b[o]*sc;
        } else { int j = p-512; v = bs2[j] + bn2[j]; }
        bY2[p] = f2bf(v);
      }
    }
    return;
  }
  const float* src; u16* dst; int srcNC, NTtot, ntOff, ntCnt, Fh, perm;
  if      (b < 32)  { src=l1Wih; dst=BY1; srcNC=256; NTtot=24; ntOff=0;  ntCnt=16; Fh=64;  perm=2; }
  else if (b < 48)  { src=fcs1W; dst=BY1; srcNC=128; NTtot=24; ntOff=16; ntCnt=8;  Fh=0;   perm=0; b-=32; }
  else if (b < 80)  { src=l1Whh; dst=BW1; srcNC=256; NTtot=16; ntOff=0;  ntCnt=16; Fh=64;  perm=1; b-=48; }
  else if (b < 96)  { src=fcn1W; dst=BN1; srcNC=128; NTtot=8;  ntOff=0;  ntCnt=8;  Fh=0;   perm=0; b-=80; }
  else if (b < 224) { src=l2Wih; dst=BY2; srcNC=512; NTtot=40; ntOff=0;  ntCnt=32; Fh=128; perm=2; b-=96; }
  else if (b < 256) { src=fcs2W; dst=BY2; srcNC=128; NTtot=40; ntOff=32; ntCnt=8;  Fh=0;   perm=0; b-=224; }
  else if (b < 384) { src=l2Whh; dst=BW2; srcNC=512; NTtot=32; ntOff=0;  ntCnt=32; Fh=128; perm=1; b-=256; }
  else              { src=fcn2W; dst=BN2; srcNC=128; NTtot=8;  ntOff=0;  ntCnt=8;  Fh=0;   perm=0; b-=384; }
  const int ntl = b % ntCnt, kt = b / ntCnt;
  const int n = lane & 15, qq = lane >> 4;
  int pr = ntl*16 + n;
  int o; float scale = 1.0f;
  if (perm == 1) {
    int g = (pr>>4)&3;
    o = g*Fh + ((pr>>6)<<4) + (pr&15);
    scale = (g==2) ? 2.88539008f : -1.44269504f;
  } else if (perm == 2) {
    int g = pr&3;
    o = g*Fh + ((pr>>6)<<4) + ((pr>>2)&15);
    scale = (g==2) ? 2.88539008f : -1.44269504f;
  } else o = pr;
  u16* d = dst + ((size_t)((kt*NTtot + ntOff + ntl)*64 + lane))*8;
#pragma unroll
  for (int j = 0; j < 8; ++j) {
    int k = kt*32 + qq*8 + j;
    d[j] = f2bf(src[(size_t)k*srcNC + o] * scale);
  }
}

// ---------------- MFMA GEMM: out_bf16[32rows x NTT*16] = A@B + bias -----------
template<int KT, int NTT, int AF32>
__global__ __launch_bounds__(256, 2)
void gemm_kernel(const void* __restrict__ Ain,
                 const u16* __restrict__ Bpk,
                 const u16* __restrict__ biasbf,
                 u16* __restrict__ out, int out_stride)
{
  constexpr int KA  = KT*32;
  constexpr int NTW = NTT/4;
  constexpr int STR = KA + 8;
  __shared__ __align__(16) u16 a_lds[32*STR];
  const int tid  = threadIdx.x;
  const int base = blockIdx.x*32;
  {
    const int sub = tid & 7, rowl = tid >> 3;
    if constexpr (AF32) {
      const float* src = (const float*)Ain + (size_t)(base+rowl)*KA;
#pragma unroll
      for (int cc = 0; cc < KA/32; ++cc) {
        int e0 = (cc*8+sub)*4;
        float4 v = *(const float4*)(src + e0);
        ushort4 bv;
        bv.x = f2bf(v.x); bv.y = f2bf(v.y); bv.z = f2bf(v.z); bv.w = f2bf(v.w);
        *(ushort4*)(void*)(a_lds + rowl*STR + e0) = bv;
      }
    } else {
      const u16* src = (const u16*)Ain + (size_t)(base+rowl)*KA;
#pragma unroll
      for (int cc = 0; cc < KA/64; ++cc) {
        int e0 = (cc*8+sub)*8;
        uint4 v = *(const uint4*)(const void*)(src + e0);
        *(uint4*)(void*)(a_lds + rowl*STR + e0) = v;
      }
    }
  }
  __syncthreads();
  const int lane = tid & 63, w = tid >> 6;
  const int lc = lane & 15, q = lane >> 4;
  f32x4 acc[2][NTW];
  f32x4 z = {0.f,0.f,0.f,0.f};
#pragma unroll
  for (int m = 0; m < 2; ++m)
#pragma unroll
    for (int j = 0; j < NTW; ++j) acc[m][j] = z;
#pragma unroll
  for (int kt = 0; kt < KT; ++kt) {
    bf16x8 af0 = *(const bf16x8*)(const void*)(a_lds + lc*STR      + kt*32 + q*8);
    bf16x8 af1 = *(const bf16x8*)(const void*)(a_lds + (lc+16)*STR + kt*32 + q*8);
#pragma unroll
    for (int j = 0; j < NTW; ++j) {
      bf16x8 bf = *(const bf16x8*)(const void*)(Bpk + ((size_t)((kt*NTT + w*NTW + j)*64 + lane))*8);
      acc[0][j] = mfma16(af0, bf, acc[0][j]);
      acc[1][j] = mfma16(af1, bf, acc[1][j]);
    }
  }
#pragma unroll
  for (int m = 0; m < 2; ++m)
#pragma unroll
    for (int j = 0; j < NTW; ++j) {
      int col = (w*NTW + j)*16 + lc;
#pragma unroll
      for (int r = 0; r < 4; ++r) {
        int row = base + m*16 + q*4 + r;
        out[(size_t)row*out_stride + col] = f2bf(acc[m][j][r] + bf2f(biasbf[col]));
      }
    }
}

// ---------------- LSTM layer 2: C-init + EARLY prefetch ------------------------
// gates[16 x 4F] = MFMA(h_{t-1}, Whh, C = Y[nbr[:,t]]), prescaled.
// y(t+1) gather issued right after C-init consumes yv -> full MFMA+pointwise
// body of slack before the barrier's vmcnt(0) drain.
template<int KT, int MW>
__global__ __launch_bounds__(KT*128, MW)
void lstm_kernel(const int* __restrict__ nbr,
                 const u16* __restrict__ Y, int nctot,
                 const u16* __restrict__ Bpk,
                 const u16* __restrict__ BN,
                 const u16* __restrict__ Sp, int s_stride, int s_coloff,
                 u16* __restrict__ out)
{
  constexpr int F   = KT*32;
  constexpr int NW  = KT*2;
  constexpr int NTT = KT*8;
  constexpr int STR = F + 8;
  __shared__ __align__(16) u16 h_lds[2][16*STR];
  __shared__ int nbr_s[256];
  const int tid  = threadIdx.x;
  const int base = blockIdx.x * 16;
  const int lane = tid & 63, w = tid >> 6;
  const int lc = lane & 15, q = lane >> 4;

  for (int i = tid; i < 256; i += NW*64) nbr_s[i] = nbr[base*16 + i];

  bf16x8 bfr[KT][4];
#pragma unroll
  for (int kt = 0; kt < KT; ++kt)
#pragma unroll
    for (int g = 0; g < 4; ++g)
      bfr[kt][g] = *(const bf16x8*)(const void*)(Bpk + ((size_t)((kt*NTT + w*4 + g)*64 + lane))*8);

  f32x2 cs[2];
  cs[0] = (f32x2){0.f,0.f}; cs[1] = (f32x2){0.f,0.f};
  __syncthreads();

  const char* Yb = (const char*)Y;
  const unsigned rowbytes = (unsigned)nctot * 2u;
  const unsigned lanebyte = (unsigned)(w*64 + lc*4) * 2u;
  const int wcol = w*16 + lc;

  uint2 yv[4];
#pragma unroll
  for (int r = 0; r < 4; ++r) {
    unsigned vr = (unsigned)nbr_s[(q*4 + r)*16];
    yv[r] = *(const uint2*)(const void*)(Yb + (vr*rowbytes + lanebyte));
  }

  for (int t = 0; t < 16; ++t) {
    const u16* hr = h_lds[t & 1];
    u16*       hw = h_lds[(t & 1) ^ 1];
    // C-init from gathered Y (gate-interleaved: .x = i|f, .y = g|o)
    f32x4 acc[4];
#pragma unroll
    for (int r = 0; r < 4; ++r) {
      acc[0][r] = asf(yv[r].x << 16);
      acc[1][r] = asf(yv[r].x & 0xffff0000u);
      acc[2][r] = asf(yv[r].y << 16);
      acc[3][r] = asf(yv[r].y & 0xffff0000u);
    }
    // EARLY prefetch: yv free after extraction; loads overlap MFMA + pointwise
    if (t < 15) {
#pragma unroll
      for (int r = 0; r < 4; ++r) {
        unsigned vr = (unsigned)nbr_s[(q*4 + r)*16 + t + 1];
        yv[r] = *(const uint2*)(const void*)(Yb + (vr*rowbytes + lanebyte));
      }
    }
    if (t != 0) {
#pragma unroll
      for (int kt = 0; kt < KT; ++kt) {
        bf16x8 af = *(const bf16x8*)(const void*)(hr + lc*STR + kt*32 + q*8);
#pragma unroll
        for (int g = 0; g < 4; ++g) acc[g] = mfma16(af, bfr[kt][g], acc[g]);
      }
    }
#pragma unroll
    for (int rp = 0; rp < 2; ++rp) {
      f32x2 gi = (f32x2){acc[0][2*rp], acc[0][2*rp+1]};
      f32x2 gf = (f32x2){acc[1][2*rp], acc[1][2*rp+1]};
      f32x2 gg = (f32x2){acc[2][2*rp], acc[2][2*rp+1]};
      f32x2 go = (f32x2){acc[3][2*rp], acc[3][2*rp+1]};
      f32x2 c  = sig2p(gf)*cs[rp] + sig2p(gi)*tanh2p(gg);
      cs[rp] = c;
      f32x2 hh = sig2p(go)*tanh2(c);
      unsigned pkd = cvt_pk_bf16(hh.x, hh.y);
      int r0 = q*4 + 2*rp;
      hw[r0*STR + wcol]     = (u16)pkd;
      hw[(r0+1)*STR + wcol] = (u16)(pkd >> 16);
    }
    __syncthreads();
  }

  constexpr int CPW = 8 / NW;
  const u16* hf = h_lds[0];
#pragma unroll
  for (int cc2 = 0; cc2 < CPW; ++cc2) {
    const int nt = w*CPW + cc2;
    f32x4 a2 = {0.f,0.f,0.f,0.f};
#pragma unroll
    for (int kt = 0; kt < KT; ++kt) {
      bf16x8 nf = *(const bf16x8*)(const void*)(BN + ((size_t)((kt*8 + nt)*64 + lane))*8);
      bf16x8 af = *(const bf16x8*)(const void*)(hf + lc*STR + kt*32 + q*8);
      a2 = mfma16(af, nf, a2);
    }
    const int col = nt*16 + lc;
#pragma unroll
    for (int r = 0; r < 4; ++r) {
      int row = base + q*4 + r;
      float v = a2[r] + bf2f(Sp[(size_t)row*s_stride + s_coloff + col]);
      out[(size_t)row*H_ + col] = f2bf(sigf(v));
    }
  }
}

// ---------------- layer-1 LSTM with fused fc epilogue AND Y2 GEMM ------------
__global__ __launch_bounds__(256, 6)
void lstm1_y2(const int* __restrict__ nbr,
              const u16* __restrict__ Y1,        // [N x 384] gates(256,prescaled)+S(128)
              const u16* __restrict__ Bpk,       // Whh1
              const u16* __restrict__ BN,        // fcn1W
              const u16* __restrict__ BY2,       // [Wih2 perm2 | fcs2W], K=128, NTT=40
              const u16* __restrict__ bY2,       // 640
              u16* __restrict__ Y2)              // [N x 640]
{
  constexpr int STR = 72;
  __shared__ __align__(16) u16 h_lds[2][16*STR];
  __shared__ __align__(16) u16 hs[16*136];
  __shared__ int nbr_s[256];
  const int tid  = threadIdx.x;
  const int base = blockIdx.x * 16;
  const int lane = tid & 63, w = tid >> 6;
  const int lc = lane & 15, q = lane >> 4;

  nbr_s[tid] = nbr[base*16 + tid];

  bf16x8 bfr[2][4];
#pragma unroll
  for (int kt = 0; kt < 2; ++kt)
#pragma unroll
    for (int g = 0; g < 4; ++g)
      bfr[kt][g] = *(const bf16x8*)(const void*)(Bpk + ((size_t)((kt*16 + w*4 + g)*64 + lane))*8);

  f32x2 cs[2];
  cs[0] = (f32x2){0.f,0.f}; cs[1] = (f32x2){0.f,0.f};
  __syncthreads();

  const char* Yb = (const char*)Y1;
  const unsigned lanebyte = (unsigned)(w*64 + lc*4) * 2u;
  const int wcol = w*16 + lc;

  uint2 yv[4];
#pragma unroll
  for (int r = 0; r < 4; ++r) {
    unsigned vr = (unsigned)nbr_s[(q*4 + r)*16];
    yv[r] = *(const uint2*)(const void*)(Yb + (vr*768u + lanebyte));
  }

  for (int t = 0; t < 16; ++t) {
    const u16* hr = h_lds[t & 1];
    u16*       hw = h_lds[(t & 1) ^ 1];
    f32x4 acc[4];
#pragma unroll
    for (int r = 0; r < 4; ++r) {
      acc[0][r] = asf(yv[r].x << 16);
      acc[1][r] = asf(yv[r].x & 0xffff0000u);
      acc[2][r] = asf(yv[r].y << 16);
      acc[3][r] = asf(yv[r].y & 0xffff0000u);
    }
    // EARLY prefetch (same rationale as lstm_kernel)
    if (t < 15) {
#pragma unroll
      for (int r = 0; r < 4; ++r) {
        unsigned vr = (unsigned)nbr_s[(q*4 + r)*16 + t + 1];
        yv[r] = *(const uint2*)(const void*)(Yb + (vr*768u + lanebyte));
      }
    }
    if (t != 0) {
#pragma unroll
      for (int kt = 0; kt < 2; ++kt) {
        bf16x8 af = *(const bf16x8*)(const void*)(hr + lc*STR + kt*32 + q*8);
#pragma unroll
        for (int g = 0; g < 4; ++g) acc[g] = mfma16(af, bfr[kt][g], acc[g]);
      }
    }
#pragma unroll
    for (int rp = 0; rp < 2; ++rp) {
      f32x2 gi = (f32x2){acc[0][2*rp], acc[0][2*rp+1]};
      f32x2 gf = (f32x2){acc[1][2*rp], acc[1][2*rp+1]};
      f32x2 gg = (f32x2){acc[2][2*rp], acc[2][2*rp+1]};
      f32x2 go = (f32x2){acc[3][2*rp], acc[3][2*rp+1]};
      f32x2 c  = sig2p(gf)*cs[rp] + sig2p(gi)*tanh2p(gg);
      cs[rp] = c;
      f32x2 hh = sig2p(go)*tanh2(c);
      unsigned pkd = cvt_pk_bf16(hh.x, hh.y);
      int r0 = q*4 + 2*rp;
      hw[r0*STR + wcol]     = (u16)pkd;
      hw[(r0+1)*STR + wcol] = (u16)(pkd >> 16);
    }
    __syncthreads();
  }

  // ---- epilogue 1: h1 = sigmoid(S + h_K@Wn) -> hs (LDS) ----
  const u16* hf = h_lds[0];
#pragma unroll
  for (int cc2 = 0; cc2 < 2; ++cc2) {
    const int nt = w*2 + cc2;
    f32x4 a2 = {0.f,0.f,0.f,0.f};
#pragma unroll
    for (int kt = 0; kt < 2; ++kt) {
      bf16x8 nf = *(const bf16x8*)(const void*)(BN + ((size_t)((kt*8 + nt)*64 + lane))*8);
      bf16x8 af = *(const bf16x8*)(const void*)(hf + lc*STR + kt*32 + q*8);
      a2 = mfma16(af, nf, a2);
    }
    const int col = nt*16 + lc;
#pragma unroll
    for (int r = 0; r < 4; ++r) {
      int row = base + q*4 + r;
      float v = a2[r] + bf2f(Y1[(size_t)row*384 + 256 + col]);
      hs[(q*4 + r)*136 + col] = f2bf(sigf(v));
    }
  }
  __syncthreads();

  // ---- epilogue 2: Y2 = h1 @ BY2 + bY2 (K=128, 640 cols; 10 ntiles/wave) ----
#pragma unroll
  for (int j = 0; j < 10; ++j) {
    const int nt = w*10 + j;
    const int col = nt*16 + lc;
    float bv = bf2f(bY2[col]);
    f32x4 acc;
#pragma unroll
    for (int r = 0; r < 4; ++r) acc[r] = bv;
#pragma unroll
    for (int kt = 0; kt < 4; ++kt) {
      bf16x8 af = *(const bf16x8*)(const void*)(hs + lc*136 + kt*32 + q*8);
      bf16x8 bf = *(const bf16x8*)(const void*)(BY2 + ((size_t)((kt*40 + nt)*64 + lane))*8);
      acc = mfma16(af, bf, acc);
    }
#pragma unroll
    for (int r = 0; r < 4; ++r)
      Y2[(size_t)(base + q*4 + r)*640 + col] = f2bf(acc[r]);
  }
}

// ---------------- readout + head (graphs = 32 contiguous nodes) --------------
__global__ __launch_bounds__(128)
void head_kernel(const u16* __restrict__ h2, const float* __restrict__ rwW,
                 const float* __restrict__ rwb,
                 const float* __restrict__ h1W, const float* __restrict__ h1b,
                 const float* __restrict__ h2W, const float* __restrict__ h2b,
                 float* __restrict__ out)
{
  __shared__ float h2s[32*H_];
  __shared__ float part[32*4];
  __shared__ float wv[32];
  __shared__ float gemb[2*H_];
  __shared__ float y1[H_];
  const int g = blockIdx.x, t = threadIdx.x;
  for (int r = 0; r < 32; ++r)
    h2s[r*H_ + t] = bf2f(h2[(size_t)(g*32 + r)*H_ + t]);
  __syncthreads();
  { int r = t>>2, qq = t&3; float p = 0.f;
    for (int h = qq*32; h < qq*32+32; ++h) p += h2s[r*H_+h]*rwW[h];
    part[r*4+qq] = p; }
  __syncthreads();
  if (t < 32) wv[t] = sigf(part[t*4]+part[t*4+1]+part[t*4+2]+part[t*4+3]+rwb[0]);
  __syncthreads();
  { float wsum=0.f, mx=-3.402823466e38f;
    for (int r = 0; r < 32; ++r) { float v = h2s[r*H_+t]; wsum += wv[r]*v; mx = fmaxf(mx,v); }
    gemb[t]=wsum; gemb[H_+t]=mx; }
  __syncthreads();
  { float a = h1b[t];
    for (int k = 0; k < 2*H_; ++k) a += gemb[k]*h1W[k*H_+t];
    y1[t]=sigf(a); }
  __syncthreads();
  if (t < T_) {
    float a = h2b[t];
    for (int h = 0; h < H_; ++h) a += y1[h]*h2W[h*T_+t];
    out[(size_t)g*T_+t] = sigf(a);
  }
}

extern "C" void kernel_launch(void* const* d_in, const int* in_sizes, int n_in,
                              void* d_out, int out_size, void* d_ws, size_t ws_size,
                              hipStream_t stream) {
  const float* n_feat = (const float*)d_in[0];
  const int*   nbr    = (const int*)d_in[1];
  const float* l1Wih = (const float*)d_in[4];
  const float* l1Whh = (const float*)d_in[5];
  const float* l1b   = (const float*)d_in[6];
  const float* fcs1W = (const float*)d_in[7];
  const float* fcs1b = (const float*)d_in[8];
  const float* fcn1W = (const float*)d_in[9];
  const float* fcn1b = (const float*)d_in[10];
  const float* l2Wih = (const float*)d_in[11];
  const float* l2Whh = (const float*)d_in[12];
  const float* l2b   = (const float*)d_in[13];
  const float* fcs2W = (const float*)d_in[14];
  const float* fcs2b = (const float*)d_in[15];
  const float* fcn2W = (const float*)d_in[16];
  const float* fcn2b = (const float*)d_in[17];
  const float* rwW   = (const float*)d_in[18];
  const float* rwb   = (const float*)d_in[19];
  const float* h1W   = (const float*)d_in[20];
  const float* h1b   = (const float*)d_in[21];
  const float* h2W   = (const float*)d_in[22];
  const float* h2b   = (const float*)d_in[23];

  char* ws = (char*)d_ws;

  if (ws_size >= 67600000) {
    u16* Y1 = (u16*)(ws);                        // [N x 384] = 25.2 MB
    u16* Y2 = (u16*)(ws + 25165824);             // [N x 640] = 41.9 MB
    u16* h2 = (u16*)(ws);                        // reuse Y1 (dead after lstm1_y2)
    char* wt = ws + 67108864;
    u16* BY1 = (u16*)(wt);
    u16* BW1 = (u16*)(wt + 49152);
    u16* BN1 = (u16*)(wt + 81920);
    u16* BY2 = (u16*)(wt + 98304);
    u16* BW2 = (u16*)(wt + 262144);
    u16* BN2 = (u16*)(wt + 393216);
    u16* bY1 = (u16*)(wt + 425984);
    u16* bY2 = (u16*)(wt + 426752);

    pack_all<<<417, 64, 0, stream>>>(l1Wih, fcs1W, l1Whh, fcn1W,
                                     l2Wih, fcs2W, l2Whh, fcn2W,
                                     l1b, fcs1b, fcn1b, l2b, fcs2b, fcn2b,
                                     BY1, BW1, BN1, BY2, BW2, BN2, bY1, bY2);
    gemm_kernel<2,24,1><<<1024, 256, 0, stream>>>(n_feat, BY1, bY1, Y1, 384);
    lstm1_y2<<<2048, 256, 0, stream>>>(nbr, Y1, BW1, BN1, BY2, bY2, Y2);
    lstm_kernel<4,4><<<2048, 512, 0, stream>>>(nbr, Y2, 640, BW2, BN2, Y2, 640, 512, h2);
    head_kernel<<<G_, 128, 0, stream>>>(h2, rwW, rwb, h1W, h1b, h2W, h2b, (float*)d_out);
  } else {
    // fallback: same structure but shared Y buffer via gemm2 path
    u16* Y   = (u16*)(ws);
    u16* h1  = (u16*)(ws + 41943040);
    u16* h2  = (u16*)(ws + 50331648);
    char* wt = ws + 58720256;
    u16* BY1 = (u16*)(wt);
    u16* BW1 = (u16*)(wt + 49152);
    u16* BN1 = (u16*)(wt + 81920);
    u16* BY2 = (u16*)(wt + 98304);
    u16* BW2 = (u16*)(wt + 262144);
    u16* BN2 = (u16*)(wt + 393216);
    u16* bY1 = (u16*)(wt + 425984);
    u16* bY2 = (u16*)(wt + 426752);

    pack_all<<<417, 64, 0, stream>>>(l1Wih, fcs1W, l1Whh, fcn1W,
                                     l2Wih, fcs2W, l2Whh, fcn2W,
                                     l1b, fcs1b, fcn1b, l2b, fcs2b, fcn2b,
                                     BY1, BW1, BN1, BY2, BW2, BN2, bY1, bY2);
    gemm_kernel<2,24,1><<<1024, 256, 0, stream>>>(n_feat, BY1, bY1, Y, 384);
    lstm_kernel<2,6><<<2048, 256, 0, stream>>>(nbr, Y, 384, BW1, BN1, Y, 384, 256, h1);
    gemm_kernel<4,40,0><<<1024, 256, 0, stream>>>(h1, BY2, bY2, Y, 640);
    lstm_kernel<4,4><<<2048, 512, 0, stream>>>(nbr, Y, 640, BW2, BN2, Y, 640, 512, h2);
    head_kernel<<<G_, 128, 0, stream>>>(h2, rwW, rwb, h1W, h1b, h2W, h2b, (float*)d_out);
  }
}